// Round 1
// baseline (315.746 us; speedup 1.0000x reference)
//
#include <hip/hip_runtime.h>
#include <cstdint>
#include <cstddef>

#define Bn 16
#define Cn 64
#define Hn 256
#define Wn 256
#define HWn (Hn * Wn)          // 65536
#define PIX (Bn * HWn)         // 1048576

#define TH 8
#define TW 64

// ---------------- kernel C: pack weight signs + per-co scaling ----------------
__global__ void pack_weights(const float* __restrict__ w,
                             uint64_t* __restrict__ wbits,
                             float* __restrict__ scaling) {
    int co = threadIdx.x;                  // 64 threads, 1 block
    if (co >= Cn) return;
    float asum = 0.f;
    uint64_t wb[9] = {0, 0, 0, 0, 0, 0, 0, 0, 0};
    const float* wp = w + (size_t)co * (Cn * 9);
    for (int ci = 0; ci < Cn; ++ci) {
        #pragma unroll
        for (int t = 0; t < 9; ++t) {
            float v = wp[ci * 9 + t];
            asum += fabsf(v);
            wb[t] |= (uint64_t)(v > 0.f) << ci;
        }
    }
    #pragma unroll
    for (int t = 0; t < 9; ++t) wbits[co * 9 + t] = wb[t];
    scaling[co] = asum * (1.f / (Cn * 9));
}

// ---------------- kernel A: binarize + bit-pack activations ----------------
// thread -> 4 consecutive pixels (float4 loads), loops over 64 channels
__global__ __launch_bounds__(256) void pack_act(const float* __restrict__ x,
                                                const float* __restrict__ rdk,
                                                const float* __restrict__ rdb,
                                                uint64_t* __restrict__ actbits) {
    int t = blockIdx.x * 256 + threadIdx.x;     // 0 .. PIX/4-1
    int p0 = t << 2;                            // pixel index, multiple of 4
    int n  = p0 >> 16;                          // / HWn
    int hw = p0 & (HWn - 1);
    const float* xb = x + (size_t)n * Cn * HWn + hw;
    uint64_t b0 = 0, b1 = 0, b2 = 0, b3 = 0;
    for (int ci = 0; ci < Cn; ++ci) {
        float k  = rdk[ci];
        float bb = rdb[ci];
        const float4 v = *reinterpret_cast<const float4*>(xb + (size_t)ci * HWn);
        uint64_t bit = 1ull << ci;
        if (fmaf(v.x, k, bb) > 0.f) b0 |= bit;
        if (fmaf(v.y, k, bb) > 0.f) b1 |= bit;
        if (fmaf(v.z, k, bb) > 0.f) b2 |= bit;
        if (fmaf(v.w, k, bb) > 0.f) b3 |= bit;
    }
    uint64_t* o = actbits + p0;
    o[0] = b0; o[1] = b1; o[2] = b2; o[3] = b3;
}

// ---------------- kernel B: XNOR-popcount conv + fused epilogue ----------------
__global__ __launch_bounds__(256) void bconv(const uint64_t* __restrict__ actbits,
                                             const uint64_t* __restrict__ wbits_g,
                                             const float* __restrict__ scaling_g,
                                             const float* __restrict__ x,
                                             const float* __restrict__ b0_g,
                                             const float* __restrict__ pw_g,
                                             const float* __restrict__ b1_g,
                                             float* __restrict__ out) {
    __shared__ uint64_t s_a[TH + 2][TW + 2];
    __shared__ uint64_t s_v[TH + 2][TW + 2];
    __shared__ uint64_t s_wb[Cn * 9];
    __shared__ float s_scale[Cn], s_b0[Cn], s_pw[Cn], s_b1[Cn];

    const int tid = threadIdx.x;
    const int w0 = blockIdx.x * TW;
    const int h0 = blockIdx.y * TH;
    const int n  = blockIdx.z;

    // stage activation-bit halo tile (+ validity words for padding)
    for (int i = tid; i < (TH + 2) * (TW + 2); i += 256) {
        int r = i / (TW + 2), c = i % (TW + 2);
        int gh = h0 - 1 + r, gw = w0 - 1 + c;
        uint64_t a = 0, v = 0;
        if (gh >= 0 && gh < Hn && gw >= 0 && gw < Wn) {
            a = actbits[(size_t)n * HWn + gh * Wn + gw];
            v = ~0ull;
        }
        s_a[r][c] = a;
        s_v[r][c] = v;
    }
    for (int i = tid; i < Cn * 9; i += 256) s_wb[i] = wbits_g[i];
    if (tid < Cn) {
        s_scale[tid] = scaling_g[tid];
        s_b0[tid]    = b0_g[tid];
        s_pw[tid]    = pw_g[tid];
        s_b1[tid]    = b1_g[tid];
    }
    __syncthreads();

    const int lane    = tid & 63;
    const int wave    = tid >> 6;
    const int co_base = wave * 16;

    for (int r = 0; r < TH; ++r) {
        uint64_t a[9], v[9];
        #pragma unroll
        for (int dh = 0; dh < 3; ++dh)
            #pragma unroll
            for (int dw = 0; dw < 3; ++dw) {
                a[dh * 3 + dw] = s_a[r + dh][lane + dw];
                v[dh * 3 + dw] = s_v[r + dh][lane + dw];
            }
        // 64 * (#valid taps): v[t] is all-ones or zero, so (v[t] & 64) is 64 or 0
        int vsum = 0;
        #pragma unroll
        for (int t = 0; t < 9; ++t) vsum += (int)(v[t] & 64);

        const size_t gpix = (size_t)(h0 + r) * Wn + w0 + lane;
        #pragma unroll 4
        for (int c = 0; c < 16; ++c) {
            const int co = co_base + c;
            const uint64_t* wb = &s_wb[co * 9];
            int acc = 0;
            #pragma unroll
            for (int t = 0; t < 9; ++t)
                acc += __popcll(v[t] & (a[t] ^ wb[t]));
            float ysum = (float)(vsum - 2 * acc);
            float y = fmaf(s_scale[co], ysum, s_b0[co]);
            y = (y >= 0.f) ? y : y * s_pw[co];
            y += s_b1[co];
            const size_t gi = ((size_t)(n * Cn + co)) * HWn + gpix;
            out[gi] = y + x[gi];
        }
    }
}

// ---------------- host launcher ----------------
extern "C" void kernel_launch(void* const* d_in, const int* in_sizes, int n_in,
                              void* d_out, int out_size, void* d_ws, size_t ws_size,
                              hipStream_t stream) {
    const float* x      = (const float*)d_in[0];
    const float* rd_k   = (const float*)d_in[1];
    const float* rd_b   = (const float*)d_in[2];
    // d_in[3] = beta: unused in forward (STE forward = hard sign)
    const float* conv_w = (const float*)d_in[4];
    const float* pb0    = (const float*)d_in[5];
    const float* pw     = (const float*)d_in[6];
    const float* pb1    = (const float*)d_in[7];
    float* out = (float*)d_out;

    uint8_t* ws = (uint8_t*)d_ws;
    uint64_t* actbits = (uint64_t*)ws;                              // 8 MiB
    uint64_t* wbits   = (uint64_t*)(ws + (size_t)PIX * 8);          // 4608 B
    float*    scaling = (float*)(ws + (size_t)PIX * 8 + Cn * 9 * 8);// 256 B

    pack_weights<<<1, 64, 0, stream>>>(conv_w, wbits, scaling);
    pack_act<<<PIX / 4 / 256, 256, 0, stream>>>(x, rd_k, rd_b, actbits);
    dim3 gB(Wn / TW, Hn / TH, Bn);
    bconv<<<gB, 256, 0, stream>>>(actbits, wbits, scaling, x, pb0, pw, pb1, out);
}

// Round 2
// 258.168 us; speedup vs baseline: 1.2230x; 1.2230x over previous
//
#include <hip/hip_runtime.h>
#include <cstdint>
#include <cstddef>

#define Bn 16
#define Cn 64
#define Hn 256
#define Wn 256
#define HWn (Hn * Wn)          // 65536
#define PIX (Bn * HWn)         // 1048576

#define TH 8
#define TW 64

// ---------------- kernel C: pack weight signs + scaling + border corrections ----
// grid 64 blocks (co), 64 threads (ci). Ballot assembles the 64-channel bitmask.
__global__ __launch_bounds__(64) void pack_weights(const float* __restrict__ w,
                                                   const float* __restrict__ b0g,
                                                   const float* __restrict__ pwg,
                                                   const float* __restrict__ b1g,
                                                   uint64_t* __restrict__ wbits,
                                                   float4* __restrict__ par,
                                                   int* __restrict__ corr) {
    const int co = blockIdx.x;
    const int ci = threadIdx.x;
    const float* wp = w + ((size_t)co * Cn + ci) * 9;
    float v[9];
    float asum = 0.f;
    #pragma unroll
    for (int t = 0; t < 9; ++t) { v[t] = wp[t]; asum += fabsf(v[t]); }
    uint64_t m[9];
    #pragma unroll
    for (int t = 0; t < 9; ++t) m[t] = __ballot(v[t] > 0.f);
    #pragma unroll
    for (int off = 32; off; off >>= 1) asum += __shfl_xor(asum, off);
    if (ci == 0) {
        #pragma unroll
        for (int t = 0; t < 9; ++t) {
            wbits[co * 9 + t] = m[t];
            corr[co * 9 + t]  = 64 - 2 * (int)__popcll(m[t]);
        }
        par[co] = make_float4(asum * (1.f / (Cn * 9)), b0g[co], pwg[co], b1g[co]);
    }
}

// ---------------- kernel A: binarize + bit-pack activations ----------------
__global__ __launch_bounds__(256) void pack_act(const float* __restrict__ x,
                                                const float* __restrict__ rdk,
                                                const float* __restrict__ rdb,
                                                uint64_t* __restrict__ actbits) {
    int t = blockIdx.x * 256 + threadIdx.x;     // 0 .. PIX/4-1
    int p0 = t << 2;
    int n  = p0 >> 16;
    int hw = p0 & (HWn - 1);
    const float* xb = x + (size_t)n * Cn * HWn + hw;
    uint64_t b0 = 0, b1 = 0, b2 = 0, b3 = 0;
    for (int ci = 0; ci < Cn; ++ci) {
        float k  = rdk[ci];
        float bb = rdb[ci];
        const float4 v = *reinterpret_cast<const float4*>(xb + (size_t)ci * HWn);
        uint64_t bit = 1ull << ci;
        if (fmaf(v.x, k, bb) > 0.f) b0 |= bit;
        if (fmaf(v.y, k, bb) > 0.f) b1 |= bit;
        if (fmaf(v.z, k, bb) > 0.f) b2 |= bit;
        if (fmaf(v.w, k, bb) > 0.f) b3 |= bit;
    }
    uint64_t* o = actbits + p0;
    o[0] = b0; o[1] = b1; o[2] = b2; o[3] = b3;
}

// ---------------- kernel B: XNOR-popcount conv + fused epilogue ----------------
__global__ __launch_bounds__(256) void bconv(const uint64_t* __restrict__ actbits,
                                             const uint64_t* __restrict__ wbits,
                                             const float4* __restrict__ par,
                                             const int* __restrict__ corr,
                                             const float* __restrict__ x,
                                             float* __restrict__ out) {
    __shared__ uint64_t s_a[TH + 2][TW + 2];   // zero-filled halo for OOB
    __shared__ float4 s_par[Cn];

    const int tid = threadIdx.x;
    const int w0 = blockIdx.x * TW;
    const int h0 = blockIdx.y * TH;
    const int n  = blockIdx.z;

    for (int i = tid; i < (TH + 2) * (TW + 2); i += 256) {
        int r = i / (TW + 2), c = i % (TW + 2);
        int gh = h0 - 1 + r, gw = w0 - 1 + c;
        uint64_t a = 0;
        if (gh >= 0 && gh < Hn && gw >= 0 && gw < Wn)
            a = actbits[(size_t)n * HWn + gh * Wn + gw];
        s_a[r][c] = a;
    }
    if (tid < Cn) s_par[tid] = par[tid];
    __syncthreads();

    const int lane = tid & 63;
    const int co_base = __builtin_amdgcn_readfirstlane((tid >> 6) * 16);
    const int w = w0 + lane;
    const unsigned cmask = (w == 0) ? 0x49u : (w == Wn - 1 ? 0x124u : 0u);

    for (int r = 0; r < TH; ++r) {
        const int h = h0 + r;
        uint64_t a[9];
        #pragma unroll
        for (int dh = 0; dh < 3; ++dh)
            #pragma unroll
            for (int dw = 0; dw < 3; ++dw)
                a[dh * 3 + dw] = s_a[r + dh][lane + dw];
        const unsigned imask = cmask | ((h == 0) ? 0x7u : (h == Hn - 1 ? 0x1C0u : 0u));
        const size_t pbase = (size_t)(n * Cn) * HWn + (size_t)h * Wn + w;

        if (!__any((int)imask)) {
            // fast path: interior pixels (vast majority)
            #pragma unroll 4
            for (int c = 0; c < 16; ++c) {
                const int co = co_base + c;
                const uint64_t* wb = wbits + co * 9;
                int acc = 0;
                #pragma unroll
                for (int t = 0; t < 9; ++t) acc += (int)__popcll(a[t] ^ wb[t]);
                const int isum = 576 - 2 * acc;
                const float4 p = s_par[co];
                float y = fmaf(p.x, (float)isum, p.y);
                y = (y >= 0.f) ? y : y * p.z;
                y += p.w;
                const size_t gi = pbase + (size_t)co * HWn;
                out[gi] = y + x[gi];
            }
        } else {
            #pragma unroll 4
            for (int c = 0; c < 16; ++c) {
                const int co = co_base + c;
                const uint64_t* wb = wbits + co * 9;
                int acc = 0;
                #pragma unroll
                for (int t = 0; t < 9; ++t) acc += (int)__popcll(a[t] ^ wb[t]);
                int isum = 576 - 2 * acc;
                #pragma unroll
                for (int t = 0; t < 9; ++t)
                    if (imask & (1u << t)) isum -= corr[co * 9 + t];
                const float4 p = s_par[co];
                float y = fmaf(p.x, (float)isum, p.y);
                y = (y >= 0.f) ? y : y * p.z;
                y += p.w;
                const size_t gi = pbase + (size_t)co * HWn;
                out[gi] = y + x[gi];
            }
        }
    }
}

// ---------------- host launcher ----------------
extern "C" void kernel_launch(void* const* d_in, const int* in_sizes, int n_in,
                              void* d_out, int out_size, void* d_ws, size_t ws_size,
                              hipStream_t stream) {
    const float* x      = (const float*)d_in[0];
    const float* rd_k   = (const float*)d_in[1];
    const float* rd_b   = (const float*)d_in[2];
    // d_in[3] = beta: unused in forward (STE forward = hard sign)
    const float* conv_w = (const float*)d_in[4];
    const float* pb0    = (const float*)d_in[5];
    const float* pw     = (const float*)d_in[6];
    const float* pb1    = (const float*)d_in[7];
    float* out = (float*)d_out;

    uint8_t* ws = (uint8_t*)d_ws;
    uint64_t* actbits = (uint64_t*)ws;                                   // 8 MiB
    size_t off = (size_t)PIX * 8;
    uint64_t* wbits = (uint64_t*)(ws + off); off += (size_t)Cn * 9 * 8;  // 4608 B
    float4*   par   = (float4*)(ws + off);   off += (size_t)Cn * 16;     // 1024 B
    int*      corr  = (int*)(ws + off);                                  // 2304 B

    pack_weights<<<Cn, 64, 0, stream>>>(conv_w, pb0, pw, pb1, wbits, par, corr);
    pack_act<<<PIX / 4 / 256, 256, 0, stream>>>(x, rd_k, rd_b, actbits);
    dim3 gB(Wn / TW, Hn / TH, Bn);
    bconv<<<gB, 256, 0, stream>>>(actbits, wbits, par, corr, x, out);
}